// Round 11
// baseline (122.787 us; speedup 1.0000x reference)
//
#include <hip/hip_runtime.h>
#include <math.h>

#define KNOTS 8
#define HIDN 32
#define TT 4096
#define CC 512
#define NB 32
#define BOUNDF 5.0f
#define CT 32            // channels per block
#define CL 16            // c-lanes (each owns a channel PAIR)
#define NTG 32           // t-rows (thread groups striding over T)
#define TPT (TT / NTG)   // 128 t-steps per thread (x2 channels = 256 elems)
#define ROWS2 (CC / 2)   // 256 f32x2 per t-row

typedef float f32x2 __attribute__((ext_vector_type(2)));

// One block = one (batch, 32-channel) slice, 512 threads = 16 c-pair-lanes x 32 t-rows.
// Phase 1: read x ONCE as f32x2; exact f32 moments; pack each (even,odd) channel
//          pair to bf16x2 held in REGISTERS (128 VGPRs).
// Finalize: 32 lanes -> spline params in LDS (float2 arrays, 2-way bank = free).
// Phase 2: unpack from registers (NO global re-read), two spline chains, f32x2 NT store.
// vs R10: load/store/address instructions halved (f32x2), same register budget.
__global__ __launch_bounds__(512, 2)
void k_fused(const float* __restrict__ x, const float* __restrict__ W1,
             const float* __restrict__ b1, const float* __restrict__ W2,
             const float* __restrict__ b2, float* __restrict__ out)
{
    const int bb = blockIdx.y;               // 0..31
    const int c0 = blockIdx.x * CT;          // 0,32,...,480
    const int lc = threadIdx.x & (CL - 1);   // 0..15 (channels 2lc, 2lc+1)
    const int tg = threadIdx.x >> 4;         // 0..31 (t-row)

    __shared__ f32x2 red2[NTG][4][CL];       // (even,odd) partial moments
    __shared__ float mom[4][CT];
    __shared__ float pA[CT], pB[CT];
    __shared__ float pKx[7][CT];
    __shared__ float2 bZ[KNOTS][CT];   // (-kxl*invw, invw)
    __shared__ float2 bY[KNOTS][CT];   // (kyl, h)
    __shared__ float2 bD[KNOTS][CT];   // (d0, d0+d1)

    const size_t base2 = ((size_t)bb * TT * CC + c0) / 2 + lc + (size_t)tg * ROWS2;
    const f32x2* pxt = (const f32x2*)x + base2;

    // ---- Phase 1: read once (f32x2), exact moments, pack to bf16 regs ----
    unsigned int xp[TPT];
    float s1e = 0.f, s2e = 0.f, s3e = 0.f, s4e = 0.f;
    float s1o = 0.f, s2o = 0.f, s3o = 0.f, s4o = 0.f;
    #pragma unroll
    for (int k = 0; k < TPT; ++k) {
        const f32x2 v = pxt[(size_t)k * (NTG * ROWS2)];
        const float ve = v.x, vo = v.y;
        const float ve2 = ve * ve, vo2 = vo * vo;
        s1e += ve;                  s1o += vo;
        s2e = fmaf(ve,  ve,  s2e);  s2o = fmaf(vo,  vo,  s2o);
        s3e = fmaf(ve2, ve,  s3e);  s3o = fmaf(vo2, vo,  s3o);
        s4e = fmaf(ve2, ve2, s4e);  s4o = fmaf(vo2, vo2, s4o);
        unsigned int pk;
        asm("v_cvt_pk_bf16_f32 %0, %1, %2" : "=v"(pk) : "v"(ve), "v"(vo));
        xp[k] = pk;
    }
    red2[tg][0][lc] = (f32x2){s1e, s1o};
    red2[tg][1][lc] = (f32x2){s2e, s2o};
    red2[tg][2][lc] = (f32x2){s3e, s3o};
    red2[tg][3][lc] = (f32x2){s4e, s4o};
    __syncthreads();

    if (threadIdx.x < 64) {
        const int m = threadIdx.x >> 4, c = threadIdx.x & (CL - 1);
        f32x2 acc = (f32x2){0.f, 0.f};
        #pragma unroll
        for (int g = 0; g < NTG; ++g) acc += red2[g][m][c];
        mom[m][2*c]   = acc.x;
        mom[m][2*c+1] = acc.y;
    }
    __syncthreads();

    // ---- Finalize: one lane per channel ----
    if (threadIdx.x < CT) {
        const int c = threadIdx.x;
        const float n  = (float)TT;
        const float t1 = mom[0][c], t2 = mom[1][c], t3 = mom[2][c], t4 = mom[3][c];
        const float mu  = t1 / n;
        const float ex2 = t2 / n, ex3 = t3 / n, ex4 = t4 / n;
        float var = (t2 - n * mu * mu) / (n - 1.f);
        var = fmaxf(var, 0.f);
        const float sig  = fmaxf(sqrtf(var), 1e-4f);
        const float inv  = 1.f / sig;
        const float mu2  = mu * mu;
        const float ez3  = ex3 - 3.f * mu * ex2 + 2.f * mu * mu2;
        const float ez4  = ex4 - 4.f * mu * ex3 + 6.f * mu2 * ex2 - 3.f * mu2 * mu2;
        const float inv2 = inv * inv;
        const float skew  = ez3 * inv2 * inv;
        const float ekurt = ez4 * inv2 * inv2 - 3.f;

        float hid[HIDN];
        #pragma unroll
        for (int h = 0; h < HIDN; ++h) {
            float v = fmaf(W1[2*h], skew, fmaf(W1[2*h+1], ekurt, b1[h]));
            hid[h] = fmaxf(v, 0.f);
        }

        float e[KNOTS], kxr[KNOTS+1], kyr[KNOTS+1], dr[KNOTS+1];
        {   // widths -> kx
            float mx = -1e30f;
            #pragma unroll
            for (int o = 0; o < KNOTS; ++o) {
                float acc = b2[o];
                #pragma unroll
                for (int h = 0; h < HIDN; ++h) acc = fmaf(W2[o*HIDN + h], hid[h], acc);
                e[o] = acc; mx = fmaxf(mx, acc);
            }
            float sum = 0.f;
            #pragma unroll
            for (int o = 0; o < KNOTS; ++o) { e[o] = expf(e[o] - mx); sum += e[o]; }
            const float scale = (2.f * BOUNDF) / sum;
            float cum = -BOUNDF; kxr[0] = -BOUNDF;
            #pragma unroll
            for (int o = 0; o < KNOTS; ++o) { cum = fmaf(e[o], scale, cum); kxr[o+1] = cum; }
        }
        {   // heights -> ky
            float mx = -1e30f;
            #pragma unroll
            for (int o = 0; o < KNOTS; ++o) {
                float acc = b2[KNOTS + o];
                #pragma unroll
                for (int h = 0; h < HIDN; ++h) acc = fmaf(W2[(KNOTS+o)*HIDN + h], hid[h], acc);
                e[o] = acc; mx = fmaxf(mx, acc);
            }
            float sum = 0.f;
            #pragma unroll
            for (int o = 0; o < KNOTS; ++o) { e[o] = expf(e[o] - mx); sum += e[o]; }
            const float scale = (2.f * BOUNDF) / sum;
            float cum = -BOUNDF; kyr[0] = -BOUNDF;
            #pragma unroll
            for (int o = 0; o < KNOTS; ++o) { cum = fmaf(e[o], scale, cum); kyr[o+1] = cum; }
        }
        #pragma unroll
        for (int o = 0; o < KNOTS+1; ++o) {  // derivs = softplus + 1e-3
            float acc = b2[2*KNOTS + o];
            #pragma unroll
            for (int h = 0; h < HIDN; ++h) acc = fmaf(W2[(2*KNOTS+o)*HIDN + h], hid[h], acc);
            float sp = fmaxf(acc, 0.f) + log1pf(expf(-fabsf(acc)));
            dr[o] = sp + 1e-3f;
        }

        pA[c] = inv;
        pB[c] = -mu * inv;
        #pragma unroll
        for (int j = 1; j <= 7; ++j) pKx[j-1][c] = kxr[j];
        #pragma unroll
        for (int j = 0; j < KNOTS; ++j) {
            const float w    = kxr[j+1] - kxr[j];
            const float wm   = fmaxf(w, 1e-8f);
            const float invw = 1.f / wm;
            const float h    = kyr[j+1] - kyr[j];
            bZ[j][c] = make_float2(-kxr[j] * invw, invw);
            bY[j][c] = make_float2(kyr[j], h);
            bD[j][c] = make_float2(dr[j], dr[j] + dr[j+1]);
        }
    }
    __syncthreads();

    // ---- Phase 2: unpack from registers, two spline chains, f32x2 NT store ----
    const int ce = 2*lc, co = 2*lc + 1;
    const float aE = pA[ce], bE = pB[ce];
    const float aO = pA[co], bO = pB[co];
    const float e1 = pKx[0][ce], e2 = pKx[1][ce], e3 = pKx[2][ce],
                e4 = pKx[3][ce], e5 = pKx[4][ce], e6 = pKx[5][ce],
                e7 = pKx[6][ce];
    const float o1 = pKx[0][co], o2 = pKx[1][co], o3 = pKx[2][co],
                o4 = pKx[3][co], o5 = pKx[4][co], o6 = pKx[5][co],
                o7 = pKx[6][co];
    f32x2* pot = (f32x2*)out + base2;

    #pragma unroll
    for (int k = 0; k < TPT; ++k) {
        const unsigned int u = xp[k];
        const float xe = __uint_as_float(u << 16);          // low bf16 = even ch
        const float xo = __uint_as_float(u & 0xffff0000u);  // high bf16 = odd ch

        // even channel
        const float zE = fmaf(xe, aE, bE);
        const bool  E4 = zE >= e4;
        const float EmB = E4 ? e6 : e2;
        const bool  EB = zE >= EmB;
        const float EnLo = E4 ? e5 : e1;
        const float EnHi = E4 ? e7 : e3;
        const float EmC = EB ? EnHi : EnLo;
        const bool  EC = zE >= EmC;
        const int offE = (E4 ? 4*CT : 0) + (EB ? 2*CT : 0) + (EC ? CT : 0) + ce;
        const float2 ZE = ((const float2*)bZ)[offE];
        const float2 YE = ((const float2*)bY)[offE];
        const float2 DE = ((const float2*)bD)[offE];
        const float ztE = fmaf(zE, ZE.y, ZE.x);
        const float uE  = fmaf(-ztE, ztE, ztE);
        const float sE  = YE.y * ZE.y;
        const float RE  = fmaf(-2.f, sE, DE.y);
        const float dnE = fmaf(RE, uE, sE);
        const float inE = fmaf(sE * ztE, ztE, DE.x * uE);
        const float rsE = fmaf(YE.y * inE,
                               __builtin_amdgcn_rcpf(fmaxf(dnE, 1e-8f)), YE.x);
        const float rE  = (fabsf(zE) > BOUNDF) ? zE : rsE;

        // odd channel
        const float zO = fmaf(xo, aO, bO);
        const bool  O4 = zO >= o4;
        const float OmB = O4 ? o6 : o2;
        const bool  OB = zO >= OmB;
        const float OnLo = O4 ? o5 : o1;
        const float OnHi = O4 ? o7 : o3;
        const float OmC = OB ? OnHi : OnLo;
        const bool  OC = zO >= OmC;
        const int offO = (O4 ? 4*CT : 0) + (OB ? 2*CT : 0) + (OC ? CT : 0) + co;
        const float2 ZO = ((const float2*)bZ)[offO];
        const float2 YO = ((const float2*)bY)[offO];
        const float2 DO = ((const float2*)bD)[offO];
        const float ztO = fmaf(zO, ZO.y, ZO.x);
        const float uO  = fmaf(-ztO, ztO, ztO);
        const float sO  = YO.y * ZO.y;
        const float RO  = fmaf(-2.f, sO, DO.y);
        const float dnO = fmaf(RO, uO, sO);
        const float inO = fmaf(sO * ztO, ztO, DO.x * uO);
        const float rsO = fmaf(YO.y * inO,
                               __builtin_amdgcn_rcpf(fmaxf(dnO, 1e-8f)), YO.x);
        const float rO  = (fabsf(zO) > BOUNDF) ? zO : rsO;

        const f32x2 r = {rE, rO};
        __builtin_nontemporal_store(r, &pot[(size_t)k * (NTG * ROWS2)]);
    }
}

extern "C" void kernel_launch(void* const* d_in, const int* in_sizes, int n_in,
                              void* d_out, int out_size, void* d_ws, size_t ws_size,
                              hipStream_t stream) {
    const float* x  = (const float*)d_in[0];
    const float* W1 = (const float*)d_in[1];
    const float* b1 = (const float*)d_in[2];
    const float* W2 = (const float*)d_in[3];
    const float* b2 = (const float*)d_in[4];
    float* out = (float*)d_out;

    k_fused<<<dim3(CC / CT, NB), dim3(512), 0, stream>>>(x, W1, b1, W2, b2, out);
}